// Round 1
// baseline (403.370 us; speedup 1.0000x reference)
//
#include <hip/hip_runtime.h>

typedef unsigned short u16;
typedef unsigned int   u32;
typedef __attribute__((ext_vector_type(4))) float f32x4;
typedef __attribute__((ext_vector_type(8))) short s16x8;

#define HW    36864
#define WPIX  192
#define NCH   256
#define NB    4
#define NPIX  147456
#define POS   85
#define BN_EPS 1e-5f

// workspace float offsets
#define WS_PALL    0
#define WS_YD      (WS_PALL + NB*NCH*POS)
#define WS_PSUM    (WS_YD + NB*NCH*POS)
#define WS_PSQ     (WS_PSUM + 1024)
#define WS_PSC     (WS_PSQ + 1024)
#define WS_PBI     (WS_PSC + 1024)
#define WS_CONTRIB (WS_PBI + 1024)
#define WS_FSUM    (WS_CONTRIB + NB*NCH*64)
#define WS_FSQ     (WS_FSUM + 256)
#define WS_FSC     (WS_FSQ + 256)
#define WS_FBI     (WS_FSC + 256)

__device__ __forceinline__ u16 f2bf(float f) {
  u32 u = __builtin_bit_cast(u32, f);
  u += 0x7fffu + ((u >> 16) & 1u);
  return (u16)(u >> 16);
}

// K1: per-(b,c) plane -> block maxes at 24x24 (64), 48x48 (16), 96x96 (4), 192x192 (1)
__global__ __launch_bounds__(192) void k_pool(const float* __restrict__ x, float* __restrict__ wsb) {
  __shared__ float sm[8][4][48];
  __shared__ float sp[84];
  int bc = blockIdx.x;                       // b*256 + c
  const float* base = x + (size_t)bc * HW;
  int t = threadIdx.x;
  int cg = t % 48, rg = t / 48;
  if (bc == 0) {                             // zero stats accumulators (used by later kernels)
    for (int i = t; i < 2048; i += 192) wsb[WS_PSUM + i] = 0.f;
    for (int i = t; i < 512;  i += 192) wsb[WS_FSUM + i] = 0.f;
  }
  #pragma unroll
  for (int byi = 0; byi < 8; byi++) {
    float mm = -3.4e38f;
    #pragma unroll
    for (int rr = 0; rr < 6; rr++) {
      int r = byi*24 + rg + 4*rr;
      f32x4 v = *(const f32x4*)(base + r*WPIX + cg*4);
      mm = fmaxf(mm, fmaxf(fmaxf(v.x, v.y), fmaxf(v.z, v.w)));
    }
    sm[byi][rg][cg] = mm;
  }
  __syncthreads();
  size_t pb = WS_PALL + (size_t)bc * POS;
  if (t < 64) {
    int by = t >> 3, bx = t & 7;
    float mm = -3.4e38f;
    for (int r2 = 0; r2 < 4; r2++)
      for (int cq = 0; cq < 6; cq++)
        mm = fmaxf(mm, sm[by][r2][bx*6 + cq]);
    sp[t] = mm;
    wsb[pb + t] = mm;
  }
  __syncthreads();
  if (t < 16) {
    int i = t >> 2, j = t & 3;
    float mm = fmaxf(fmaxf(sp[(2*i)*8 + 2*j], sp[(2*i)*8 + 2*j + 1]),
                     fmaxf(sp[(2*i+1)*8 + 2*j], sp[(2*i+1)*8 + 2*j + 1]));
    sp[64 + t] = mm;
    wsb[pb + 64 + t] = mm;
  }
  __syncthreads();
  if (t < 4) {
    int i = t >> 1, j = t & 1;
    float mm = fmaxf(fmaxf(sp[64 + (2*i)*4 + 2*j], sp[64 + (2*i)*4 + 2*j + 1]),
                     fmaxf(sp[64 + (2*i+1)*4 + 2*j], sp[64 + (2*i+1)*4 + 2*j + 1]));
    sp[80 + t] = mm;
    wsb[pb + 80 + t] = mm;
  }
  __syncthreads();
  if (t == 0)
    wsb[pb + 84] = fmaxf(fmaxf(sp[80], sp[81]), fmaxf(sp[82], sp[83]));
}

// K2: pyramid convs on distinct block values + BN stat accumulation
__global__ __launch_bounds__(256) void k_pyr(const float* __restrict__ wconv, float* __restrict__ wsb) {
  __shared__ __align__(16) float pv[256];
  int bi = blockIdx.x;                       // b*85 + pos
  int b = bi / 85, pos = bi % 85;
  int d = (pos < 64) ? 3 : (pos < 80) ? 2 : (pos < 84) ? 1 : 0;
  int t = threadIdx.x;
  pv[t] = wsb[WS_PALL + (size_t)(b*NCH + t)*POS + pos];
  __syncthreads();
  const float* wrow = wconv + ((size_t)d*NCH + t)*NCH;
  float acc = 0.f;
  #pragma unroll 4
  for (int c4 = 0; c4 < 64; c4++) {
    f32x4 wv = *(const f32x4*)(wrow + c4*4);
    f32x4 xv = *(const f32x4*)(&pv[c4*4]);
    acc += wv.x*xv.x + wv.y*xv.y + wv.z*xv.z + wv.w*xv.w;
  }
  wsb[WS_YD + (size_t)(b*NCH + t)*POS + pos] = acc;
  atomicAdd(&wsb[WS_PSUM + d*NCH + t], acc);
  atomicAdd(&wsb[WS_PSQ  + d*NCH + t], acc*acc);
}

// K3: pyramid BN scale/bias
__global__ void k_pstats(const float* __restrict__ gs, const float* __restrict__ bs, float* __restrict__ wsb) {
  int t = blockIdx.x*256 + threadIdx.x;      // 0..1023, d = t>>8
  int d = t >> 8;
  float cnt = (float)(4 << (2*d));           // B * g^2
  float mu  = wsb[WS_PSUM + t] / cnt;
  float var = wsb[WS_PSQ + t] / cnt - mu*mu;
  float sc  = gs[t] * rsqrtf(var + BN_EPS);
  wsb[WS_PSC + t] = sc;
  wsb[WS_PBI + t] = bs[t] - mu * sc;
}

// K4: contrib[b][o][8x8 cell] = sum over 1024 pyramid channels of wf[o][256+dc]*pnorm
__global__ __launch_bounds__(256) void k_contrib(const float* __restrict__ wf, float* __restrict__ wsb) {
  __shared__ __align__(16) float pn[1024];
  int bi = blockIdx.x;                       // b*64 + cell
  int b = bi >> 6, cell = bi & 63;
  int by = cell >> 3, bx = cell & 7;
  int t = threadIdx.x;
  int pos3 = cell;
  int pos2 = 64 + (by >> 1)*4 + (bx >> 1);
  int pos1 = 80 + (by >> 2)*2 + (bx >> 2);
  size_t yb = WS_YD + (size_t)(b*NCH + t)*POS;
  pn[0*NCH + t] = wsb[yb + 84]   * wsb[WS_PSC + 0*NCH + t] + wsb[WS_PBI + 0*NCH + t];
  pn[1*NCH + t] = wsb[yb + pos1] * wsb[WS_PSC + 1*NCH + t] + wsb[WS_PBI + 1*NCH + t];
  pn[2*NCH + t] = wsb[yb + pos2] * wsb[WS_PSC + 2*NCH + t] + wsb[WS_PBI + 2*NCH + t];
  pn[3*NCH + t] = wsb[yb + pos3] * wsb[WS_PSC + 3*NCH + t] + wsb[WS_PBI + 3*NCH + t];
  __syncthreads();
  const float* wrow = wf + (size_t)t*1280 + 256;
  float acc = 0.f;
  #pragma unroll 4
  for (int j = 0; j < 256; j++) {
    f32x4 wv = *(const f32x4*)(wrow + j*4);
    f32x4 xv = *(const f32x4*)(&pn[j*4]);
    acc += wv.x*xv.x + wv.y*xv.y + wv.z*xv.z + wv.w*xv.w;
  }
  wsb[WS_CONTRIB + (size_t)(b*NCH + t)*64 + cell] = acc;
}

// K5: main GEMM  y[b,o,p] = wf[o,0:256] . x[b,:,p]  (bf16 MFMA) + contrib, + channel sum/sumsq
__global__ __launch_bounds__(256) void k_main(const float* __restrict__ x, const float* __restrict__ wf,
                                              float* __restrict__ wsb, float* __restrict__ y) {
  __shared__ __align__(16) u16 wlds[4*256*8];   // [kgroup][m][8] bf16, 16KB
  __shared__ __align__(16) u16 xlds[32*66];     // [k][pitch 66 u16 = 132B], 4224B
  int wg = blockIdx.x;
  int b = wg / 576, nt = wg % 576;
  int pbase = nt * 64;
  int hrow  = nt / 3;
  int wbase = (nt % 3) * 64;
  int by8   = (hrow / 24) * 8;
  int t = threadIdx.x;
  int wave = t >> 6, l = t & 63;
  f32x4 acc[4][4];
  #pragma unroll
  for (int i = 0; i < 4; i++)
    #pragma unroll
    for (int j = 0; j < 4; j++)
      acc[i][j] = {0.f, 0.f, 0.f, 0.f};

  int m0 = t >> 3, j8 = t & 7;      // W staging: 32 m-rows x 8 quads
  int kx = t >> 4, nq = t & 15;     // X staging: 16 k-rows x 16 float4 cols
  const float* xb = x + (size_t)(b*NCH)*HW + pbase;
  int g = l >> 4, ln = l & 15;

  for (int ks = 0; ks < 8; ks++) {
    // stage W chunk [256 m][32 k] -> wlds[kq][m][8]
    #pragma unroll
    for (int i = 0; i < 8; i++) {
      int m = m0 + 32*i;
      f32x4 wv = *(const f32x4*)(wf + (size_t)m*1280 + ks*32 + j8*4);
      u16* dst = &wlds[((j8 >> 1)*256 + m)*8 + (j8 & 1)*4];
      u32 p0 = (u32)f2bf(wv.x) | ((u32)f2bf(wv.y) << 16);
      u32 p1 = (u32)f2bf(wv.z) | ((u32)f2bf(wv.w) << 16);
      ((u32*)dst)[0] = p0; ((u32*)dst)[1] = p1;
    }
    // stage X chunk [32 k][64 n] -> xlds row-major pitch 66
    #pragma unroll
    for (int i = 0; i < 2; i++) {
      int kk = kx + 16*i;
      f32x4 xv = *(const f32x4*)(xb + (size_t)(ks*32 + kk)*HW + nq*4);
      u32 p0 = (u32)f2bf(xv.x) | ((u32)f2bf(xv.y) << 16);
      u32 p1 = (u32)f2bf(xv.z) | ((u32)f2bf(xv.w) << 16);
      ((u32*)xlds)[kk*33 + nq*2]     = p0;
      ((u32*)xlds)[kk*33 + nq*2 + 1] = p1;
    }
    __syncthreads();
    // A frags: lane holds W[m = l&15 (+16*tm+64*wave)][k = 8*(l>>4)+j]
    s16x8 afr[4];
    #pragma unroll
    for (int tm = 0; tm < 4; tm++)
      afr[tm] = *(const s16x8*)&wlds[(g*256 + wave*64 + tm*16 + ln)*8];
    #pragma unroll
    for (int tn = 0; tn < 4; tn++) {
      int nb_ = tn*16 + ln;
      s16x8 bfr;
      #pragma unroll
      for (int j = 0; j < 8; j++)
        bfr[j] = (short)xlds[(8*g + j)*66 + nb_];
      #pragma unroll
      for (int tm = 0; tm < 4; tm++)
        acc[tm][tn] = __builtin_amdgcn_mfma_f32_16x16x32_bf16(afr[tm], bfr, acc[tm][tn], 0, 0, 0);
    }
    __syncthreads();
  }

  // epilogue: add contrib, store un-normalized y, accumulate channel stats
  const float* cb = wsb + WS_CONTRIB + (size_t)b*NCH*64;
  float* fsum = wsb + WS_FSUM;
  float* fsq  = wsb + WS_FSQ;
  float* ybase = y + (size_t)(b*NCH)*HW + pbase;
  #pragma unroll
  for (int tm = 0; tm < 4; tm++) {
    int ob = wave*64 + tm*16 + g*4;
    #pragma unroll
    for (int r = 0; r < 4; r++) {
      int o = ob + r;
      float s1 = 0.f, s2 = 0.f;
      #pragma unroll
      for (int tn = 0; tn < 4; tn++) {
        int n = tn*16 + ln;
        int bx = (wbase + n) / 24;
        float yv = acc[tm][tn][r] + cb[(size_t)o*64 + by8 + bx];
        ybase[(size_t)o*HW + n] = yv;
        s1 += yv; s2 += yv*yv;
      }
      s1 += __shfl_xor(s1, 1);  s2 += __shfl_xor(s2, 1);
      s1 += __shfl_xor(s1, 2);  s2 += __shfl_xor(s2, 2);
      s1 += __shfl_xor(s1, 4);  s2 += __shfl_xor(s2, 4);
      s1 += __shfl_xor(s1, 8);  s2 += __shfl_xor(s2, 8);
      if (ln == 0) { atomicAdd(&fsum[o], s1); atomicAdd(&fsq[o], s2); }
    }
  }
}

// K6: final BN scale/bias
__global__ void k_fstats(const float* __restrict__ gf, const float* __restrict__ bfv, float* __restrict__ wsb) {
  int o = threadIdx.x;
  float inv = 1.f / (float)NPIX;
  float mu  = wsb[WS_FSUM + o] * inv;
  float var = wsb[WS_FSQ + o] * inv - mu*mu;
  float sc  = gf[o] * rsqrtf(var + BN_EPS);
  wsb[WS_FSC + o] = sc;
  wsb[WS_FBI + o] = bfv[o] - mu * sc;
}

// K7: in-place normalize
__global__ __launch_bounds__(256) void k_norm(float* __restrict__ y, const float* __restrict__ wsb) {
  const float* sc = wsb + WS_FSC;
  const float* bi = wsb + WS_FBI;
  size_t i0 = (size_t)blockIdx.x*blockDim.x + threadIdx.x;
  size_t stride = (size_t)gridDim.x * blockDim.x;
  const size_t n4 = (size_t)NPIX * NCH / 4;
  for (size_t i = i0; i < n4; i += stride) {
    int ch = (int)(i / 9216) & 255;
    f32x4 v = *((const f32x4*)y + i);
    float s = sc[ch], bb = bi[ch];
    v.x = v.x*s + bb; v.y = v.y*s + bb; v.z = v.z*s + bb; v.w = v.w*s + bb;
    *((f32x4*)y + i) = v;
  }
}

extern "C" void kernel_launch(void* const* d_in, const int* in_sizes, int n_in,
                              void* d_out, int out_size, void* d_ws, size_t ws_size,
                              hipStream_t stream) {
  const float* x  = (const float*)d_in[0];
  const float* w  = (const float*)d_in[1];
  const float* gs = (const float*)d_in[2];
  const float* bs = (const float*)d_in[3];
  const float* wf = (const float*)d_in[4];
  const float* gf = (const float*)d_in[5];
  const float* bf = (const float*)d_in[6];
  float* y   = (float*)d_out;
  float* wsb = (float*)d_ws;

  k_pool   <<<NB*NCH, 192, 0, stream>>>(x, wsb);
  k_pyr    <<<NB*POS, 256, 0, stream>>>(w, wsb);
  k_pstats <<<4, 256, 0, stream>>>(gs, bs, wsb);
  k_contrib<<<NB*64, 256, 0, stream>>>(wf, wsb);
  k_main   <<<NB*576, 256, 0, stream>>>(x, wf, wsb, y);
  k_fstats <<<1, 256, 0, stream>>>(gf, bf, wsb);
  k_norm   <<<2048, 256, 0, stream>>>(y, wsb);
}

// Round 2
// 200.413 us; speedup vs baseline: 2.0127x; 2.0127x over previous
//
#include <hip/hip_runtime.h>

typedef unsigned short u16;
typedef unsigned int   u32;
typedef __attribute__((ext_vector_type(4))) float f32x4;
typedef __attribute__((ext_vector_type(8))) short s16x8;
typedef __attribute__((ext_vector_type(4))) unsigned short u16x4;

#define HW    36864
#define WPIX  192
#define NCH   256
#define NB    4
#define NPIX  147456
#define POS   85
#define BN_EPS 1e-5f
#define NBKT  16

// workspace float offsets
#define WS_PALL    0
#define WS_YD      (WS_PALL + NB*NCH*POS)          // 87040
#define WS_PSUM    (WS_YD + NB*NCH*POS)            // 174080
#define WS_PSQ     (WS_PSUM + 1024)
#define WS_PSC     (WS_PSQ + 1024)
#define WS_PBI     (WS_PSC + 1024)
#define WS_CONTRIB (WS_PBI + 1024)                 // 178176, 65536
#define WS_FSUMB   (WS_CONTRIB + NB*NCH*64)        // 243712
#define WS_FSQB    (WS_FSUMB + NBKT*256)
#define WS_FSC     (WS_FSQB + NBKT*256)
#define WS_FBI     (WS_FSC + 256)
#define WS_WPK     (WS_FBI + 256)                  // u16[65536] = 32768 floats
#define WS_YBF     (WS_WPK + 32768)
#define WS_YBF_FLOATS (NB*NCH*HW/2)                // 18874368 floats (u16 y)
#define WS_TOTAL   (WS_YBF + WS_YBF_FLOATS)

__device__ __forceinline__ u16 f2bf(float f) {
  u32 u = __builtin_bit_cast(u32, f);
  u += 0x7fffu + ((u >> 16) & 1u);
  return (u16)(u >> 16);
}
__device__ __forceinline__ float bf2f(u16 h) {
  u32 u = ((u32)h) << 16;
  return __builtin_bit_cast(float, u);
}

// K1: per-(b,c) plane -> block maxes; also zero stat accumulators
__global__ __launch_bounds__(192) void k_pool(const float* __restrict__ x, float* __restrict__ wsb) {
  __shared__ float sm[8][4][48];
  __shared__ float sp[84];
  int bc = blockIdx.x;                       // b*256 + c
  const float* base = x + (size_t)bc * HW;
  int t = threadIdx.x;
  int cg = t % 48, rg = t / 48;
  if (bc == 0) {
    for (int i = t; i < 2048; i += 192) wsb[WS_PSUM + i] = 0.f;
    for (int i = t; i < 2*NBKT*256; i += 192) wsb[WS_FSUMB + i] = 0.f;
  }
  #pragma unroll
  for (int byi = 0; byi < 8; byi++) {
    float mm = -3.4e38f;
    #pragma unroll
    for (int rr = 0; rr < 6; rr++) {
      int r = byi*24 + rg + 4*rr;
      f32x4 v = *(const f32x4*)(base + r*WPIX + cg*4);
      mm = fmaxf(mm, fmaxf(fmaxf(v.x, v.y), fmaxf(v.z, v.w)));
    }
    sm[byi][rg][cg] = mm;
  }
  __syncthreads();
  size_t pb = WS_PALL + (size_t)bc * POS;
  if (t < 64) {
    int by = t >> 3, bx = t & 7;
    float mm = -3.4e38f;
    for (int r2 = 0; r2 < 4; r2++)
      for (int cq = 0; cq < 6; cq++)
        mm = fmaxf(mm, sm[by][r2][bx*6 + cq]);
    sp[t] = mm;
    wsb[pb + t] = mm;
  }
  __syncthreads();
  if (t < 16) {
    int i = t >> 2, j = t & 3;
    float mm = fmaxf(fmaxf(sp[(2*i)*8 + 2*j], sp[(2*i)*8 + 2*j + 1]),
                     fmaxf(sp[(2*i+1)*8 + 2*j], sp[(2*i+1)*8 + 2*j + 1]));
    sp[64 + t] = mm;
    wsb[pb + 64 + t] = mm;
  }
  __syncthreads();
  if (t < 4) {
    int i = t >> 1, j = t & 1;
    float mm = fmaxf(fmaxf(sp[64 + (2*i)*4 + 2*j], sp[64 + (2*i)*4 + 2*j + 1]),
                     fmaxf(sp[64 + (2*i+1)*4 + 2*j], sp[64 + (2*i+1)*4 + 2*j + 1]));
    sp[80 + t] = mm;
    wsb[pb + 80 + t] = mm;
  }
  __syncthreads();
  if (t == 0)
    wsb[pb + 84] = fmaxf(fmaxf(sp[80], sp[81]), fmaxf(sp[82], sp[83]));
}

// K1b: pre-pack wf[:, :256] into bf16 A-fragments: wpk[((ks*4+g)*256 + m)*8 + j]
__global__ __launch_bounds__(256) void k_wpack(const float* __restrict__ wf, float* __restrict__ wsb) {
  int fid = blockIdx.x*256 + threadIdx.x;    // 0..8191
  int m = fid & 255, g = (fid >> 8) & 3, ks = fid >> 10;
  const float* src = wf + (size_t)m*1280 + ks*32 + g*8;
  f32x4 a = *(const f32x4*)src;
  f32x4 c = *(const f32x4*)(src + 4);
  u32* dst = (u32*)((u16*)(wsb + WS_WPK) + (size_t)fid*8);
  dst[0] = (u32)f2bf(a.x) | ((u32)f2bf(a.y) << 16);
  dst[1] = (u32)f2bf(a.z) | ((u32)f2bf(a.w) << 16);
  dst[2] = (u32)f2bf(c.x) | ((u32)f2bf(c.y) << 16);
  dst[3] = (u32)f2bf(c.z) | ((u32)f2bf(c.w) << 16);
}

// K2: pyramid convs on distinct block values + BN stat accumulation
__global__ __launch_bounds__(256) void k_pyr(const float* __restrict__ wconv, float* __restrict__ wsb) {
  __shared__ __align__(16) float pv[256];
  int bi = blockIdx.x;                       // b*85 + pos
  int b = bi / 85, pos = bi % 85;
  int d = (pos < 64) ? 3 : (pos < 80) ? 2 : (pos < 84) ? 1 : 0;
  int t = threadIdx.x;
  pv[t] = wsb[WS_PALL + (size_t)(b*NCH + t)*POS + pos];
  __syncthreads();
  const float* wrow = wconv + ((size_t)d*NCH + t)*NCH;
  float acc = 0.f;
  #pragma unroll 4
  for (int c4 = 0; c4 < 64; c4++) {
    f32x4 wv = *(const f32x4*)(wrow + c4*4);
    f32x4 xv = *(const f32x4*)(&pv[c4*4]);
    acc += wv.x*xv.x + wv.y*xv.y + wv.z*xv.z + wv.w*xv.w;
  }
  wsb[WS_YD + (size_t)(b*NCH + t)*POS + pos] = acc;
  atomicAdd(&wsb[WS_PSUM + d*NCH + t], acc);
  atomicAdd(&wsb[WS_PSQ  + d*NCH + t], acc*acc);
}

// K3: pyramid BN scale/bias
__global__ void k_pstats(const float* __restrict__ gs, const float* __restrict__ bs, float* __restrict__ wsb) {
  int t = blockIdx.x*256 + threadIdx.x;      // 0..1023
  int d = t >> 8;
  float cnt = (float)(4 << (2*d));
  float mu  = wsb[WS_PSUM + t] / cnt;
  float var = wsb[WS_PSQ + t] / cnt - mu*mu;
  float sc  = gs[t] * rsqrtf(var + BN_EPS);
  wsb[WS_PSC + t] = sc;
  wsb[WS_PBI + t] = bs[t] - mu * sc;
}

// K4: contrib[b][o][cell]
__global__ __launch_bounds__(256) void k_contrib(const float* __restrict__ wf, float* __restrict__ wsb) {
  __shared__ __align__(16) float pn[1024];
  int bi = blockIdx.x;                       // b*64 + cell
  int b = bi >> 6, cell = bi & 63;
  int by = cell >> 3, bx = cell & 7;
  int t = threadIdx.x;
  int pos3 = cell;
  int pos2 = 64 + (by >> 1)*4 + (bx >> 1);
  int pos1 = 80 + (by >> 2)*2 + (bx >> 2);
  size_t yb = WS_YD + (size_t)(b*NCH + t)*POS;
  pn[0*NCH + t] = wsb[yb + 84]   * wsb[WS_PSC + 0*NCH + t] + wsb[WS_PBI + 0*NCH + t];
  pn[1*NCH + t] = wsb[yb + pos1] * wsb[WS_PSC + 1*NCH + t] + wsb[WS_PBI + 1*NCH + t];
  pn[2*NCH + t] = wsb[yb + pos2] * wsb[WS_PSC + 2*NCH + t] + wsb[WS_PBI + 2*NCH + t];
  pn[3*NCH + t] = wsb[yb + pos3] * wsb[WS_PSC + 3*NCH + t] + wsb[WS_PBI + 3*NCH + t];
  __syncthreads();
  const float* wrow = wf + (size_t)t*1280 + 256;
  float acc = 0.f;
  #pragma unroll 4
  for (int j = 0; j < 256; j++) {
    f32x4 wv = *(const f32x4*)(wrow + j*4);
    f32x4 xv = *(const f32x4*)(&pn[j*4]);
    acc += wv.x*xv.x + wv.y*xv.y + wv.z*xv.z + wv.w*xv.w;
  }
  wsb[WS_CONTRIB + (size_t)(b*NCH + t)*64 + cell] = acc;
}

// K5: main GEMM  y[b,o,p] = wf[o,0:256] . x[b,:,p] (bf16 MFMA) + contrib, + channel stats
template<bool YBF>
__global__ __launch_bounds__(256) void k_main(const float* __restrict__ x,
                                              float* __restrict__ wsb, float* __restrict__ y) {
  __shared__ __align__(16) u16 xlds[2][64*40];   // [n][40 u16], 80B pitch (16B-aligned rows)
  int wg = blockIdx.x;
  int b = wg / 576, nt = wg % 576;
  int pbase = nt * 64;
  int by8   = ((nt / 3) / 24) * 8;
  int wbase = (nt % 3) * 64;
  int t = threadIdx.x;
  int wave = t >> 6, l = t & 63;
  int g = l >> 4, ln = l & 15;
  int sn = t & 63;                // staging n (column)
  int kh = t >> 6;                // staging k-octet
  const float* xb = x + (size_t)b*NCH*HW + pbase + sn;
  const u16* wpk = (const u16*)(wsb + WS_WPK);
  int mrow = wave*64 + ln;

  f32x4 acc[4][4];
  #pragma unroll
  for (int i = 0; i < 4; i++)
    #pragma unroll
    for (int j = 0; j < 4; j++)
      acc[i][j] = {0.f, 0.f, 0.f, 0.f};

  float xr0[8], xr1[8];
  s16x8 a0[4], a1[4];

  // prologue loads for ks=0
  #pragma unroll
  for (int j = 0; j < 8; j++) xr0[j] = xb[(size_t)(kh*8 + j)*HW];
  #pragma unroll
  for (int tm = 0; tm < 4; tm++)
    a0[tm] = *(const s16x8*)(wpk + ((size_t)(0*4 + g)*256 + mrow + tm*16)*8);

  #pragma unroll
  for (int ks = 0; ks < 8; ks++) {
    float    (&xr)[8] = (ks & 1) ? xr1 : xr0;
    s16x8    (&af)[4] = (ks & 1) ? a1  : a0;
    float    (&xrn)[8] = (ks & 1) ? xr0 : xr1;
    s16x8    (&afn)[4] = (ks & 1) ? a0  : a1;
    // write staged X (transposed, k-contiguous per n)
    s16x8 pk;
    #pragma unroll
    for (int j = 0; j < 8; j++) pk[j] = (short)f2bf(xr[j]);
    *(s16x8*)(&xlds[ks & 1][sn*40 + kh*8]) = pk;
    __syncthreads();
    // prefetch next K-step (overlaps MFMA below)
    if (ks < 7) {
      #pragma unroll
      for (int j = 0; j < 8; j++) xrn[j] = xb[(size_t)((ks+1)*32 + kh*8 + j)*HW];
      #pragma unroll
      for (int tm = 0; tm < 4; tm++)
        afn[tm] = *(const s16x8*)(wpk + ((size_t)((ks+1)*4 + g)*256 + mrow + tm*16)*8);
    }
    #pragma unroll
    for (int tn = 0; tn < 4; tn++) {
      s16x8 bfr = *(const s16x8*)(&xlds[ks & 1][(tn*16 + ln)*40 + g*8]);
      #pragma unroll
      for (int tm = 0; tm < 4; tm++)
        acc[tm][tn] = __builtin_amdgcn_mfma_f32_16x16x32_bf16(af[tm], bfr, acc[tm][tn], 0, 0, 0);
    }
  }

  // epilogue: add contrib, store y (bf16 in ws, or fp32 in d_out), channel stats
  const float* cb = wsb + WS_CONTRIB + (size_t)b*NCH*64;
  int bkt = wg & (NBKT - 1);
  float* fsum = wsb + WS_FSUMB + bkt*256;
  float* fsq  = wsb + WS_FSQB  + bkt*256;
  u16*   ybb  = (u16*)(wsb + WS_YBF) + (size_t)b*NCH*HW + pbase;
  float* ybf32 = y + (size_t)b*NCH*HW + pbase;
  #pragma unroll
  for (int tm = 0; tm < 4; tm++) {
    int ob = wave*64 + tm*16 + g*4;
    #pragma unroll
    for (int r = 0; r < 4; r++) {
      int o = ob + r;
      float s1 = 0.f, s2 = 0.f;
      #pragma unroll
      for (int tn = 0; tn < 4; tn++) {
        int n = tn*16 + ln;
        int bx = (wbase + n) / 24;
        float yv = acc[tm][tn][r] + cb[(size_t)o*64 + by8 + bx];
        if (YBF) {
          u16 h = f2bf(yv);
          float yr = bf2f(h);
          ybb[(size_t)o*HW + n] = h;
          s1 += yr; s2 += yr*yr;
        } else {
          ybf32[(size_t)o*HW + n] = yv;
          s1 += yv; s2 += yv*yv;
        }
      }
      s1 += __shfl_xor(s1, 1);  s2 += __shfl_xor(s2, 1);
      s1 += __shfl_xor(s1, 2);  s2 += __shfl_xor(s2, 2);
      s1 += __shfl_xor(s1, 4);  s2 += __shfl_xor(s2, 4);
      s1 += __shfl_xor(s1, 8);  s2 += __shfl_xor(s2, 8);
      if (ln == 0) { atomicAdd(&fsum[o], s1); atomicAdd(&fsq[o], s2); }
    }
  }
}

// K6: reduce buckets -> final BN scale/bias
__global__ void k_fstats(const float* __restrict__ gf, const float* __restrict__ bfv, float* __restrict__ wsb) {
  int o = threadIdx.x;
  float s1 = 0.f, s2 = 0.f;
  #pragma unroll
  for (int i = 0; i < NBKT; i++) {
    s1 += wsb[WS_FSUMB + i*256 + o];
    s2 += wsb[WS_FSQB  + i*256 + o];
  }
  float inv = 1.f / (float)NPIX;
  float mu  = s1 * inv;
  float var = s2 * inv - mu*mu;
  float sc  = gf[o] * rsqrtf(var + BN_EPS);
  wsb[WS_FSC + o] = sc;
  wsb[WS_FBI + o] = bfv[o] - mu * sc;
}

// K7: normalize (read bf16 y from ws or fp32 in-place) -> fp32 out
template<bool YBF>
__global__ __launch_bounds__(256) void k_norm(float* __restrict__ out, const float* __restrict__ wsb) {
  int bid = blockIdx.x;                      // 4096: (plane, quarter)
  int plane = bid >> 2, q = bid & 3;
  int c = plane & 255;
  float sc = wsb[WS_FSC + c], bi = wsb[WS_FBI + c];
  size_t base4 = ((size_t)plane*HW + q*(HW/4)) >> 2;   // float4 index
  int t = threadIdx.x;
  if (YBF) {
    const u16* yb = (const u16*)(wsb + WS_YBF);
    #pragma unroll
    for (int it = 0; it < 9; it++) {
      size_t i4 = base4 + it*256 + t;
      u16x4 v = *(const u16x4*)(yb + i4*4);
      f32x4 o;
      o.x = bf2f(v.x)*sc + bi;
      o.y = bf2f(v.y)*sc + bi;
      o.z = bf2f(v.z)*sc + bi;
      o.w = bf2f(v.w)*sc + bi;
      ((f32x4*)out)[i4] = o;
    }
  } else {
    #pragma unroll
    for (int it = 0; it < 9; it++) {
      size_t i4 = base4 + it*256 + t;
      f32x4 v = ((f32x4*)out)[i4];
      v.x = v.x*sc + bi; v.y = v.y*sc + bi; v.z = v.z*sc + bi; v.w = v.w*sc + bi;
      ((f32x4*)out)[i4] = v;
    }
  }
}

extern "C" void kernel_launch(void* const* d_in, const int* in_sizes, int n_in,
                              void* d_out, int out_size, void* d_ws, size_t ws_size,
                              hipStream_t stream) {
  const float* x  = (const float*)d_in[0];
  const float* w  = (const float*)d_in[1];
  const float* gs = (const float*)d_in[2];
  const float* bs = (const float*)d_in[3];
  const float* wf = (const float*)d_in[4];
  const float* gf = (const float*)d_in[5];
  const float* bf = (const float*)d_in[6];
  float* y   = (float*)d_out;
  float* wsb = (float*)d_ws;

  bool ybf = ws_size >= (size_t)WS_TOTAL * sizeof(float);

  k_pool   <<<NB*NCH, 192, 0, stream>>>(x, wsb);
  k_wpack  <<<32, 256, 0, stream>>>(wf, wsb);
  k_pyr    <<<NB*POS, 256, 0, stream>>>(w, wsb);
  k_pstats <<<4, 256, 0, stream>>>(gs, bs, wsb);
  k_contrib<<<NB*64, 256, 0, stream>>>(wf, wsb);
  if (ybf) k_main<true> <<<NB*576, 256, 0, stream>>>(x, wsb, y);
  else     k_main<false><<<NB*576, 256, 0, stream>>>(x, wsb, y);
  k_fstats <<<1, 256, 0, stream>>>(gf, bf, wsb);
  if (ybf) k_norm<true> <<<4096, 256, 0, stream>>>(y, wsb);
  else     k_norm<false><<<4096, 256, 0, stream>>>(y, wsb);
}